// Round 2
// baseline (685.388 us; speedup 1.0000x reference)
//
#include <hip/hip_runtime.h>
#include <math.h>

#define N_ 8
#define L_ 8192
#define C_ 256
#define H_ 4
#define D_ 64
#define NH_ (N_*H_)
#define NCH 16
#define CHUNK (L_/NCH)           // 512
#define Q_ ((size_t)N_*H_*L_*D_) // 16,777,216 elements per tensor

// bf16 helpers (manual, RNE) --------------------------------------------------
__device__ inline ushort f2b(float f){
  uint x = __float_as_uint(f);
  uint r = (x + 0x7fffu + ((x >> 16) & 1u)) >> 16;
  return (ushort)r;
}
__device__ inline float b2f(ushort u){
  return __uint_as_float(((uint)u) << 16);
}
__device__ inline uint pk2(float a, float b){
  return (uint)f2b(a) | ((uint)f2b(b) << 16);
}
__device__ inline void unpack8(uint4 p, float* f){
  f[0]=__uint_as_float(p.x<<16); f[1]=__uint_as_float(p.x&0xffff0000u);
  f[2]=__uint_as_float(p.y<<16); f[3]=__uint_as_float(p.y&0xffff0000u);
  f[4]=__uint_as_float(p.z<<16); f[5]=__uint_as_float(p.z&0xffff0000u);
  f[6]=__uint_as_float(p.w<<16); f[7]=__uint_as_float(p.w&0xffff0000u);
}

// ---------------------------------------------------------------------------
// K1: qkv = x @ qkv_w^T fused with mask + l2norm(q), l2norm(k).
// Output col block (64 wide) == one (s,h): rows get normalized in-block.
// Writes bf16 q/k/v in (N,H,L,D) layout.
// ---------------------------------------------------------------------------
__global__ __launch_bounds__(256) void qkv_gemm_norm(const float* __restrict__ x,
                                                     const float* __restrict__ w,
                                                     const int* __restrict__ mask,
                                                     ushort* __restrict__ qb,
                                                     ushort* __restrict__ kb,
                                                     ushort* __restrict__ vb) {
  __shared__ float At[16][68];
  __shared__ float Bt[16][68];
  const int tid = threadIdx.x;
  const int ty = tid >> 4, tx = tid & 15;
  const int lr = tid >> 2, lc = (tid & 3) << 2;
  const float* Ab = x + (size_t)blockIdx.x * 64 * C_;
  const float* Bb = w + (size_t)blockIdx.y * 64 * C_;
  float acc[4][4] = {};
  for (int k0 = 0; k0 < C_; k0 += 16) {
    float4 a4 = *(const float4*)(Ab + (size_t)lr * C_ + k0 + lc);
    float4 b4 = *(const float4*)(Bb + (size_t)lr * C_ + k0 + lc);
    At[lc+0][lr]=a4.x; At[lc+1][lr]=a4.y; At[lc+2][lr]=a4.z; At[lc+3][lr]=a4.w;
    Bt[lc+0][lr]=b4.x; Bt[lc+1][lr]=b4.y; Bt[lc+2][lr]=b4.z; Bt[lc+3][lr]=b4.w;
    __syncthreads();
#pragma unroll
    for (int kk = 0; kk < 16; ++kk) {
      float4 av = *(const float4*)&At[kk][ty*4];
      float4 bv = *(const float4*)&Bt[kk][tx*4];
      float a[4] = {av.x, av.y, av.z, av.w};
      float b[4] = {bv.x, bv.y, bv.z, bv.w};
#pragma unroll
      for (int i = 0; i < 4; ++i)
#pragma unroll
        for (int j = 0; j < 4; ++j)
          acc[i][j] += a[i]*b[j];
    }
    __syncthreads();
  }
  const int s = blockIdx.y >> 2, h = blockIdx.y & 3;
  // l2norm for q (s==0) and k (s==1): row = 64 cols of this block.
  if (s < 2) {
#pragma unroll
    for (int i = 0; i < 4; ++i) {
      float ss = acc[i][0]*acc[i][0] + acc[i][1]*acc[i][1]
               + acc[i][2]*acc[i][2] + acc[i][3]*acc[i][3];
      ss += __shfl_xor(ss, 1); ss += __shfl_xor(ss, 2);
      ss += __shfl_xor(ss, 4); ss += __shfl_xor(ss, 8);
      float inv = 1.0f / sqrtf(ss);
#pragma unroll
      for (int j = 0; j < 4; ++j) acc[i][j] *= inv;
    }
  }
  ushort* dst = (s == 0) ? qb : (s == 1) ? kb : vb;
#pragma unroll
  for (int i = 0; i < 4; ++i) {
    const int m = blockIdx.x*64 + ty*4 + i;
    const int nn = m >> 13, l = m & (L_-1);
    ushort4 pkv;
    if (s == 0 && mask[(size_t)nn*L_ + l] == 0) {
      const ushort mb = f2b(-0.125f);
      pkv = make_ushort4(mb, mb, mb, mb);
    } else {
      pkv = make_ushort4(f2b(acc[i][0]), f2b(acc[i][1]),
                         f2b(acc[i][2]), f2b(acc[i][3]));
    }
    *(ushort4*)&dst[(((size_t)nn*H_ + h)*L_ + l)*D_ + tx*4] = pkv;
  }
}

// ---------------------------------------------------------------------------
// K3: per (n,h,chunk): partial kv[d][e] = sum_l k_hat[l][d]*v[l][e]. bf16 in,
// fp32 accum/out. Deterministic.
// ---------------------------------------------------------------------------
__global__ __launch_bounds__(256) void kv_partial(const ushort* __restrict__ kb,
                                                  const ushort* __restrict__ vb,
                                                  float* __restrict__ part) {
  const int nh = blockIdx.x, ch = blockIdx.y;
  const size_t base = ((size_t)nh*L_ + (size_t)ch*CHUNK) * 64;
  __shared__ float ks[32][68];
  __shared__ float vs[32][68];
  const int tid = threadIdx.x;
  const int dB = tid >> 4, eB = tid & 15;
  const int lr = tid >> 3, lc = (tid & 7) << 3;
  float acc[4][4] = {};
  for (int l0 = 0; l0 < CHUNK; l0 += 32) {
    uint4 kp = *(const uint4*)(kb + base + (size_t)(l0+lr)*64 + lc);
    uint4 vp = *(const uint4*)(vb + base + (size_t)(l0+lr)*64 + lc);
    float kf[8], vf[8];
    unpack8(kp, kf); unpack8(vp, vf);
    *(float4*)&ks[lr][lc]   = make_float4(kf[0],kf[1],kf[2],kf[3]);
    *(float4*)&ks[lr][lc+4] = make_float4(kf[4],kf[5],kf[6],kf[7]);
    *(float4*)&vs[lr][lc]   = make_float4(vf[0],vf[1],vf[2],vf[3]);
    *(float4*)&vs[lr][lc+4] = make_float4(vf[4],vf[5],vf[6],vf[7]);
    __syncthreads();
#pragma unroll 8
    for (int l = 0; l < 32; ++l) {
      float4 k4 = *(const float4*)&ks[l][dB*4];
      float4 v4 = *(const float4*)&vs[l][eB*4];
      float kk[4] = {k4.x,k4.y,k4.z,k4.w};
      float vv[4] = {v4.x,v4.y,v4.z,v4.w};
#pragma unroll
      for (int i = 0; i < 4; ++i)
#pragma unroll
        for (int j = 0; j < 4; ++j)
          acc[i][j] += kk[i]*vv[j];
    }
    __syncthreads();
  }
  float* P = part + ((size_t)nh*NCH + ch)*4096;
#pragma unroll
  for (int i = 0; i < 4; ++i)
#pragma unroll
    for (int j = 0; j < 4; ++j)
      P[(dB*4+i)*64 + eB*4+j] = acc[i][j];
}

// ---------------------------------------------------------------------------
// K4: reduce partials, fold 1/pi.
// ---------------------------------------------------------------------------
__global__ __launch_bounds__(256) void kv_reduce(const float* __restrict__ part,
                                                 float* __restrict__ kvf) {
  const int nh = blockIdx.x;
  for (int i = threadIdx.x; i < 4096; i += 256) {
    float s = 0.f;
#pragma unroll
    for (int c = 0; c < NCH; ++c)
      s += part[((size_t)nh*NCH + c)*4096 + i];
    kvf[(size_t)nh*4096 + i] = s * 0.31830988618379067f;
  }
}

// ---------------------------------------------------------------------------
// K5: fused: attn = l2norm(0.5 v + q_hat @ kv') + conv9(v)   (per head, LDS)
//            out  = attn @ proj_w^T + proj_b                  (from LDS)
// One block per (n, 64-row l-tile). kv' held in 64 VGPRs per lane.
// ---------------------------------------------------------------------------
__global__ __launch_bounds__(256) void attn_proj(const ushort* __restrict__ qb,
                                                 const ushort* __restrict__ vb,
                                                 const float* __restrict__ kvf,
                                                 const float* __restrict__ dwc,
                                                 const float* __restrict__ pw,
                                                 const float* __restrict__ pb,
                                                 float* __restrict__ out) {
  __shared__ __align__(16) char sm[52800];
  ushort (*attn_s)[264] = (ushort(*)[264])sm;               // 33792 B
  ushort (*qs)[72]      = (ushort(*)[72])(sm + 33792);      //  9216 B
  ushort (*vsm)[68]     = (ushort(*)[68])(sm + 33792+9216); //  9792 B
  ushort (*Ws)[64]      = (ushort(*)[64])(sm + 33792);      // overlays qs (8192 B)
  const int tid = threadIdx.x;
  const int n = blockIdx.y;
  const int l0 = blockIdx.x * 64;
  const int e = tid & 63, wv = tid >> 6;
  float kvreg[64];

  for (int h = 0; h < H_; ++h) {
    const int nh = n*H_ + h;
    if (h) __syncthreads();
    { // q tile 64x64 bf16
      const int row = tid >> 2, c0 = (tid & 3) << 4;
      const ushort* src = qb + ((size_t)nh*L_ + l0 + row)*64 + c0;
      uint4 a0 = *(const uint4*)src;
      uint4 a1 = *(const uint4*)(src + 8);
      *(uint4*)&qs[row][c0]   = a0;
      *(uint4*)&qs[row][c0+8] = a1;
    }
    { // v halo tile 72x64 bf16 (zero-padded)
      for (int r = tid >> 2; r < 72; r += 64) {
        const int lg = l0 - 4 + r;
        const int c0 = (tid & 3) << 4;
        uint4 a0 = make_uint4(0,0,0,0), a1 = make_uint4(0,0,0,0);
        if ((unsigned)lg < (unsigned)L_) {
          const ushort* src = vb + ((size_t)nh*L_ + lg)*64 + c0;
          a0 = *(const uint4*)src;
          a1 = *(const uint4*)(src + 8);
        }
        *(uint2*)&vsm[r][c0]    = make_uint2(a0.x, a0.y);
        *(uint2*)&vsm[r][c0+4]  = make_uint2(a0.z, a0.w);
        *(uint2*)&vsm[r][c0+8]  = make_uint2(a1.x, a1.y);
        *(uint2*)&vsm[r][c0+12] = make_uint2(a1.z, a1.w);
      }
    }
    { // kv column e into registers (coalesced, L2-resident)
      const float* kvp = kvf + (size_t)nh*4096;
#pragma unroll
      for (int d = 0; d < 64; ++d) kvreg[d] = kvp[d*64 + e];
    }
    float wcv[9];
#pragma unroll
    for (int j = 0; j < 9; ++j) wcv[j] = dwc[h*9 + j];
    __syncthreads();
    for (int rr = 0; rr < 16; ++rr) {
      const int r = wv*16 + rr;
      float a = 0.f;
#pragma unroll
      for (int d0 = 0; d0 < 64; d0 += 8) {
        uint4 qp = *(const uint4*)&qs[r][d0];   // broadcast read
        float qf[8]; unpack8(qp, qf);
#pragma unroll
        for (int j = 0; j < 8; ++j) a += qf[j]*kvreg[d0+j];
      }
      a += 0.5f * b2f(vsm[r+4][e]);
      float ss = a*a;
      ss += __shfl_xor(ss, 1);  ss += __shfl_xor(ss, 2);
      ss += __shfl_xor(ss, 4);  ss += __shfl_xor(ss, 8);
      ss += __shfl_xor(ss, 16); ss += __shfl_xor(ss, 32);
      float ov = a / sqrtf(ss);
      float cv = 0.f;
#pragma unroll
      for (int j = 0; j < 9; ++j) cv += b2f(vsm[r+j][e]) * wcv[j];
      attn_s[r][h*64 + e] = f2b(ov + cv);
    }
  }
  __syncthreads();

  // phase B: out tile (64 x 256) = attn_s @ pw^T + pb
  const int ty = tid >> 4, tx = tid & 15;
  for (int oc = 0; oc < 4; ++oc) {
    float acc[4][4] = {};
    for (int kc = 0; kc < 4; ++kc) {
      __syncthreads();
      { // stage W[oc*64..][kc*64..] 64x64 as bf16 with XOR swizzle
        const int row = tid >> 2, c0 = (tid & 3) << 4;
        const float* src = pw + (size_t)(oc*64 + row)*256 + kc*64 + c0;
        float4 f0 = *(const float4*)(src);
        float4 f1 = *(const float4*)(src + 4);
        float4 f2 = *(const float4*)(src + 8);
        float4 f3 = *(const float4*)(src + 12);
        uint4 p0 = make_uint4(pk2(f0.x,f0.y), pk2(f0.z,f0.w),
                              pk2(f1.x,f1.y), pk2(f1.z,f1.w));
        uint4 p1 = make_uint4(pk2(f2.x,f2.y), pk2(f2.z,f2.w),
                              pk2(f3.x,f3.y), pk2(f3.z,f3.w));
        const int g0 = ((c0 >> 3)     ^ (row & 7)) << 3;
        const int g1 = (((c0 >> 3)+1) ^ (row & 7)) << 3;
        *(uint4*)&Ws[row][g0] = p0;
        *(uint4*)&Ws[row][g1] = p1;
      }
      __syncthreads();
#pragma unroll
      for (int cc = 0; cc < 64; cc += 8) {
        float a8[4][8], b8[4][8];
#pragma unroll
        for (int i = 0; i < 4; ++i) {
          uint4 ap = *(const uint4*)&attn_s[ty*4+i][kc*64 + cc]; // broadcast
          unpack8(ap, a8[i]);
        }
#pragma unroll
        for (int j = 0; j < 4; ++j) {
          const int r2 = j*16 + tx;
          uint4 bp = *(const uint4*)&Ws[r2][((cc >> 3) ^ (r2 & 7)) << 3];
          unpack8(bp, b8[j]);
        }
#pragma unroll
        for (int i = 0; i < 4; ++i)
#pragma unroll
          for (int j = 0; j < 4; ++j)
#pragma unroll
            for (int c = 0; c < 8; ++c)
              acc[i][j] += a8[i][c]*b8[j][c];
      }
    }
#pragma unroll
    for (int i = 0; i < 4; ++i) {
      const int m = l0 + ty*4 + i;
#pragma unroll
      for (int j = 0; j < 4; ++j) {
        const int o = oc*64 + j*16 + tx;
        out[((size_t)n*L_ + m)*C_ + o] = acc[i][j] + pb[o];
      }
    }
  }
}

extern "C" void kernel_launch(void* const* d_in, const int* in_sizes, int n_in,
                              void* d_out, int out_size, void* d_ws, size_t ws_size,
                              hipStream_t stream) {
  const float* x      = (const float*)d_in[0];
  const int*   mask   = (const int*)d_in[1];
  const float* qkv_w  = (const float*)d_in[2];
  const float* proj_w = (const float*)d_in[3];
  const float* proj_b = (const float*)d_in[4];
  const float* dconv_w= (const float*)d_in[5];
  float* out = (float*)d_out;

  // workspace: 3 bf16 tensors (32 MB each) + fp32 partials (~8.9 MB) = ~110 MB
  ushort* qb = (ushort*)d_ws;
  ushort* kb = qb + Q_;
  ushort* vb = kb + Q_;
  float* part = (float*)(vb + Q_);
  float* kvf  = part + (size_t)NH_*NCH*4096;

  qkv_gemm_norm<<<dim3(1024, 12), 256, 0, stream>>>(x, qkv_w, mask, qb, kb, vb);
  kv_partial   <<<dim3(NH_, NCH), 256, 0, stream>>>(kb, vb, part);
  kv_reduce    <<<dim3(NH_),      256, 0, stream>>>(part, kvf);
  attn_proj    <<<dim3(L_/64, N_), 256, 0, stream>>>(qb, vb, kvf, dconv_w,
                                                     proj_w, proj_b, out);
}

// Round 3
// 417.859 us; speedup vs baseline: 1.6402x; 1.6402x over previous
//
#include <hip/hip_runtime.h>
#include <math.h>

#define N_ 8
#define L_ 8192
#define C_ 256
#define H_ 4
#define D_ 64
#define NH_ (N_*H_)
#define NCH 16
#define CHUNK (L_/NCH)           // 512
#define Q_ ((size_t)N_*H_*L_*D_) // 16,777,216 elements per tensor

typedef float f32x4 __attribute__((ext_vector_type(4)));
typedef short short8 __attribute__((ext_vector_type(8)));

// bf16 helpers (manual, RNE) --------------------------------------------------
__device__ inline ushort f2b(float f){
  uint x = __float_as_uint(f);
  uint r = (x + 0x7fffu + ((x >> 16) & 1u)) >> 16;
  return (ushort)r;
}
__device__ inline float b2f(ushort u){
  return __uint_as_float(((uint)u) << 16);
}
__device__ inline uint pk2(float a, float b){
  return (uint)f2b(a) | ((uint)f2b(b) << 16);
}
__device__ inline void unpack8(uint4 p, float* f){
  f[0]=__uint_as_float(p.x<<16); f[1]=__uint_as_float(p.x&0xffff0000u);
  f[2]=__uint_as_float(p.y<<16); f[3]=__uint_as_float(p.y&0xffff0000u);
  f[4]=__uint_as_float(p.z<<16); f[5]=__uint_as_float(p.z&0xffff0000u);
  f[6]=__uint_as_float(p.w<<16); f[7]=__uint_as_float(p.w&0xffff0000u);
}

// ---------------------------------------------------------------------------
// K0: qkv_w (768x256 fp32) -> bf16
// ---------------------------------------------------------------------------
__global__ __launch_bounds__(256) void conv_w(const float* __restrict__ w,
                                              ushort* __restrict__ wb) {
  const int i = (blockIdx.x*256 + threadIdx.x) * 4;
  float4 f = *(const float4*)(w + i);
  *(ushort4*)&wb[i] = make_ushort4(f2b(f.x), f2b(f.y), f2b(f.z), f2b(f.w));
}

// ---------------------------------------------------------------------------
// K1: qkv = x @ qkv_w^T via bf16 MFMA, fused fp32->bf16 A-staging and
// mask + l2norm epilogue. BM=128, BN=256, BK=32, 512 thr = 8 waves (2Mx4N),
// wave tile 64x64 = exactly one (s,h) 64-col block.
// Writes bf16 q/k/v in (N,H,L,D).
// ---------------------------------------------------------------------------
__global__ __launch_bounds__(512) void qkv_gemm_mfma(const float* __restrict__ x,
                                                     const ushort* __restrict__ wb,
                                                     const int* __restrict__ mask,
                                                     ushort* __restrict__ qb,
                                                     ushort* __restrict__ kb,
                                                     ushort* __restrict__ vb) {
  __shared__ ushort As[128][32];   // 8 KB  [m][k]
  __shared__ ushort Bs[256][32];   // 16 KB [n][k]
  const int tid = threadIdx.x;
  const int lane = tid & 63;
  const int wid = tid >> 6, wm = wid >> 2, wn = wid & 3;
  const int gm0 = blockIdx.x * 128;
  const int gn0 = blockIdx.y * 256;

  f32x4 acc[4][4] = {};

  // staging indices
  const int ar = tid >> 2, akc = (tid & 3) << 3;   // A: row 0..127, k-chunk 0/8/16/24
  const int br = tid >> 1, bkc = (tid & 1) << 4;   // B: row 0..255, k-chunk 0/16

  for (int k0 = 0; k0 < C_; k0 += 32) {
    if (k0) __syncthreads();
    { // A: fp32 -> bf16 on the fly
      const float* src = x + (size_t)(gm0 + ar)*C_ + k0 + akc;
      float4 f0 = *(const float4*)(src);
      float4 f1 = *(const float4*)(src + 4);
      uint4 p = make_uint4(pk2(f0.x,f0.y), pk2(f0.z,f0.w),
                           pk2(f1.x,f1.y), pk2(f1.z,f1.w));
      *(uint4*)&As[ar][akc] = p;
    }
    { // B: bf16 direct
      const ushort* src = wb + (size_t)(gn0 + br)*C_ + k0 + bkc;
      uint4 p0 = *(const uint4*)(src);
      uint4 p1 = *(const uint4*)(src + 8);
      *(uint4*)&Bs[br][bkc]     = p0;
      *(uint4*)&Bs[br][bkc + 8] = p1;
    }
    __syncthreads();
    const int kc = (lane >> 4) << 3;
    short8 a[4], b[4];
#pragma unroll
    for (int mi = 0; mi < 4; ++mi)
      a[mi] = *(const short8*)&As[wm*64 + mi*16 + (lane & 15)][kc];
#pragma unroll
    for (int ni = 0; ni < 4; ++ni)
      b[ni] = *(const short8*)&Bs[wn*64 + ni*16 + (lane & 15)][kc];
#pragma unroll
    for (int mi = 0; mi < 4; ++mi)
#pragma unroll
      for (int ni = 0; ni < 4; ++ni)
        acc[mi][ni] = __builtin_amdgcn_mfma_f32_16x16x32_bf16(
            a[mi], b[ni], acc[mi][ni], 0, 0, 0);
  }

  // epilogue: C/D layout col=lane&15, row=(lane>>4)*4+j
  const int sh = blockIdx.y*4 + wn;
  const int s = sh >> 2, h = sh & 3;
  ushort* dst = (s == 0) ? qb : (s == 1) ? kb : vb;
#pragma unroll
  for (int mi = 0; mi < 4; ++mi) {
    const int rbase = gm0 + wm*64 + mi*16 + ((lane >> 4) << 2);
#pragma unroll
    for (int j = 0; j < 4; ++j) {
      const int gr = rbase + j;
      const int nn = gr >> 13, l = gr & (L_-1);
      float v0 = acc[mi][0][j], v1 = acc[mi][1][j],
            v2 = acc[mi][2][j], v3 = acc[mi][3][j];
      if (s < 2) { // l2norm across the 64 cols of this head block
        float ss = v0*v0 + v1*v1 + v2*v2 + v3*v3;
        ss += __shfl_xor(ss, 1); ss += __shfl_xor(ss, 2);
        ss += __shfl_xor(ss, 4); ss += __shfl_xor(ss, 8);
        const float inv = 1.0f / sqrtf(ss);
        v0 *= inv; v1 *= inv; v2 *= inv; v3 *= inv;
      }
      const bool masked = (s == 0) && (mask[(size_t)nn*L_ + l] == 0);
      const size_t base = (((size_t)nn*H_ + h)*L_ + l)*D_ + (lane & 15);
      if (masked) {
        const ushort mb = 0xBE00u;  // bf16(-0.125)
        dst[base] = mb; dst[base+16] = mb; dst[base+32] = mb; dst[base+48] = mb;
      } else {
        dst[base]    = f2b(v0); dst[base+16] = f2b(v1);
        dst[base+32] = f2b(v2); dst[base+48] = f2b(v3);
      }
    }
  }
}

// ---------------------------------------------------------------------------
// K3: per (n,h,chunk): partial kv[d][e] = sum_l k_hat[l][d]*v[l][e]. bf16 in,
// fp32 accum/out. Deterministic.
// ---------------------------------------------------------------------------
__global__ __launch_bounds__(256) void kv_partial(const ushort* __restrict__ kb,
                                                  const ushort* __restrict__ vb,
                                                  float* __restrict__ part) {
  const int nh = blockIdx.x, ch = blockIdx.y;
  const size_t base = ((size_t)nh*L_ + (size_t)ch*CHUNK) * 64;
  __shared__ float ks[32][68];
  __shared__ float vs[32][68];
  const int tid = threadIdx.x;
  const int dB = tid >> 4, eB = tid & 15;
  const int lr = tid >> 3, lc = (tid & 7) << 3;
  float acc[4][4] = {};
  for (int l0 = 0; l0 < CHUNK; l0 += 32) {
    uint4 kp = *(const uint4*)(kb + base + (size_t)(l0+lr)*64 + lc);
    uint4 vp = *(const uint4*)(vb + base + (size_t)(l0+lr)*64 + lc);
    float kf[8], vf[8];
    unpack8(kp, kf); unpack8(vp, vf);
    *(float4*)&ks[lr][lc]   = make_float4(kf[0],kf[1],kf[2],kf[3]);
    *(float4*)&ks[lr][lc+4] = make_float4(kf[4],kf[5],kf[6],kf[7]);
    *(float4*)&vs[lr][lc]   = make_float4(vf[0],vf[1],vf[2],vf[3]);
    *(float4*)&vs[lr][lc+4] = make_float4(vf[4],vf[5],vf[6],vf[7]);
    __syncthreads();
#pragma unroll 8
    for (int l = 0; l < 32; ++l) {
      float4 k4 = *(const float4*)&ks[l][dB*4];
      float4 v4 = *(const float4*)&vs[l][eB*4];
      float kk[4] = {k4.x,k4.y,k4.z,k4.w};
      float vv[4] = {v4.x,v4.y,v4.z,v4.w};
#pragma unroll
      for (int i = 0; i < 4; ++i)
#pragma unroll
        for (int j = 0; j < 4; ++j)
          acc[i][j] += kk[i]*vv[j];
    }
    __syncthreads();
  }
  float* P = part + ((size_t)nh*NCH + ch)*4096;
#pragma unroll
  for (int i = 0; i < 4; ++i)
#pragma unroll
    for (int j = 0; j < 4; ++j)
      P[(dB*4+i)*64 + eB*4+j] = acc[i][j];
}

// ---------------------------------------------------------------------------
// K4: reduce partials, fold 1/pi.
// ---------------------------------------------------------------------------
__global__ __launch_bounds__(256) void kv_reduce(const float* __restrict__ part,
                                                 float* __restrict__ kvf) {
  const int nh = blockIdx.x;
  for (int i = threadIdx.x; i < 4096; i += 256) {
    float s = 0.f;
#pragma unroll
    for (int c = 0; c < NCH; ++c)
      s += part[((size_t)nh*NCH + c)*4096 + i];
    kvf[(size_t)nh*4096 + i] = s * 0.31830988618379067f;
  }
}

// ---------------------------------------------------------------------------
// K5: fused: attn = l2norm(0.5 v + q_hat @ kv') + conv9(v)   (per head, LDS)
//            out  = attn @ proj_w^T + proj_b                  (from LDS)
// ---------------------------------------------------------------------------
__global__ __launch_bounds__(256) void attn_proj(const ushort* __restrict__ qb,
                                                 const ushort* __restrict__ vb,
                                                 const float* __restrict__ kvf,
                                                 const float* __restrict__ dwc,
                                                 const float* __restrict__ pw,
                                                 const float* __restrict__ pb,
                                                 float* __restrict__ out) {
  __shared__ __align__(16) char sm[52800];
  ushort (*attn_s)[264] = (ushort(*)[264])sm;               // 33792 B
  ushort (*qs)[72]      = (ushort(*)[72])(sm + 33792);      //  9216 B
  ushort (*vsm)[68]     = (ushort(*)[68])(sm + 33792+9216); //  9792 B
  ushort (*Ws)[64]      = (ushort(*)[64])(sm + 33792);      // overlays qs (8192 B)
  const int tid = threadIdx.x;
  const int n = blockIdx.y;
  const int l0 = blockIdx.x * 64;
  const int e = tid & 63, wv = tid >> 6;
  float kvreg[64];

  for (int h = 0; h < H_; ++h) {
    const int nh = n*H_ + h;
    if (h) __syncthreads();
    { // q tile 64x64 bf16
      const int row = tid >> 2, c0 = (tid & 3) << 4;
      const ushort* src = qb + ((size_t)nh*L_ + l0 + row)*64 + c0;
      uint4 a0 = *(const uint4*)src;
      uint4 a1 = *(const uint4*)(src + 8);
      *(uint4*)&qs[row][c0]   = a0;
      *(uint4*)&qs[row][c0+8] = a1;
    }
    { // v halo tile 72x64 bf16 (zero-padded)
      for (int r = tid >> 2; r < 72; r += 64) {
        const int lg = l0 - 4 + r;
        const int c0 = (tid & 3) << 4;
        uint4 a0 = make_uint4(0,0,0,0), a1 = make_uint4(0,0,0,0);
        if ((unsigned)lg < (unsigned)L_) {
          const ushort* src = vb + ((size_t)nh*L_ + lg)*64 + c0;
          a0 = *(const uint4*)src;
          a1 = *(const uint4*)(src + 8);
        }
        *(uint2*)&vsm[r][c0]    = make_uint2(a0.x, a0.y);
        *(uint2*)&vsm[r][c0+4]  = make_uint2(a0.z, a0.w);
        *(uint2*)&vsm[r][c0+8]  = make_uint2(a1.x, a1.y);
        *(uint2*)&vsm[r][c0+12] = make_uint2(a1.z, a1.w);
      }
    }
    { // kv column e into registers (coalesced, L2-resident)
      const float* kvp = kvf + (size_t)nh*4096;
#pragma unroll
      for (int d = 0; d < 64; ++d) kvreg[d] = kvp[d*64 + e];
    }
    float wcv[9];
#pragma unroll
    for (int j = 0; j < 9; ++j) wcv[j] = dwc[h*9 + j];
    __syncthreads();
    for (int rr = 0; rr < 16; ++rr) {
      const int r = wv*16 + rr;
      float a = 0.f;
#pragma unroll
      for (int d0 = 0; d0 < 64; d0 += 8) {
        uint4 qp = *(const uint4*)&qs[r][d0];   // broadcast read
        float qf[8]; unpack8(qp, qf);
#pragma unroll
        for (int j = 0; j < 8; ++j) a += qf[j]*kvreg[d0+j];
      }
      a += 0.5f * b2f(vsm[r+4][e]);
      float ss = a*a;
      ss += __shfl_xor(ss, 1);  ss += __shfl_xor(ss, 2);
      ss += __shfl_xor(ss, 4);  ss += __shfl_xor(ss, 8);
      ss += __shfl_xor(ss, 16); ss += __shfl_xor(ss, 32);
      float ov = a / sqrtf(ss);
      float cv = 0.f;
#pragma unroll
      for (int j = 0; j < 9; ++j) cv += b2f(vsm[r+j][e]) * wcv[j];
      attn_s[r][h*64 + e] = f2b(ov + cv);
    }
  }
  __syncthreads();

  // phase B: out tile (64 x 256) = attn_s @ pw^T + pb
  const int ty = tid >> 4, tx = tid & 15;
  for (int oc = 0; oc < 4; ++oc) {
    float acc[4][4] = {};
    for (int kc = 0; kc < 4; ++kc) {
      __syncthreads();
      { // stage W[oc*64..][kc*64..] 64x64 as bf16 with XOR swizzle
        const int row = tid >> 2, c0 = (tid & 3) << 4;
        const float* src = pw + (size_t)(oc*64 + row)*256 + kc*64 + c0;
        float4 f0 = *(const float4*)(src);
        float4 f1 = *(const float4*)(src + 4);
        float4 f2 = *(const float4*)(src + 8);
        float4 f3 = *(const float4*)(src + 12);
        uint4 p0 = make_uint4(pk2(f0.x,f0.y), pk2(f0.z,f0.w),
                              pk2(f1.x,f1.y), pk2(f1.z,f1.w));
        uint4 p1 = make_uint4(pk2(f2.x,f2.y), pk2(f2.z,f2.w),
                              pk2(f3.x,f3.y), pk2(f3.z,f3.w));
        const int g0 = ((c0 >> 3)     ^ (row & 7)) << 3;
        const int g1 = (((c0 >> 3)+1) ^ (row & 7)) << 3;
        *(uint4*)&Ws[row][g0] = p0;
        *(uint4*)&Ws[row][g1] = p1;
      }
      __syncthreads();
#pragma unroll
      for (int cc = 0; cc < 64; cc += 8) {
        float a8[4][8], b8[4][8];
#pragma unroll
        for (int i = 0; i < 4; ++i) {
          uint4 ap = *(const uint4*)&attn_s[ty*4+i][kc*64 + cc]; // broadcast
          unpack8(ap, a8[i]);
        }
#pragma unroll
        for (int j = 0; j < 4; ++j) {
          const int r2 = j*16 + tx;
          uint4 bp = *(const uint4*)&Ws[r2][((cc >> 3) ^ (r2 & 7)) << 3];
          unpack8(bp, b8[j]);
        }
#pragma unroll
        for (int i = 0; i < 4; ++i)
#pragma unroll
          for (int j = 0; j < 4; ++j)
#pragma unroll
            for (int c = 0; c < 8; ++c)
              acc[i][j] += a8[i][c]*b8[j][c];
      }
    }
#pragma unroll
    for (int i = 0; i < 4; ++i) {
      const int m = l0 + ty*4 + i;
#pragma unroll
      for (int j = 0; j < 4; ++j) {
        const int o = oc*64 + j*16 + tx;
        out[((size_t)n*L_ + m)*C_ + o] = acc[i][j] + pb[o];
      }
    }
  }
}

extern "C" void kernel_launch(void* const* d_in, const int* in_sizes, int n_in,
                              void* d_out, int out_size, void* d_ws, size_t ws_size,
                              hipStream_t stream) {
  const float* x      = (const float*)d_in[0];
  const int*   mask   = (const int*)d_in[1];
  const float* qkv_w  = (const float*)d_in[2];
  const float* proj_w = (const float*)d_in[3];
  const float* proj_b = (const float*)d_in[4];
  const float* dconv_w= (const float*)d_in[5];
  float* out = (float*)d_out;

  // workspace: 3 bf16 tensors (32 MB) + fp32 partials (8.5 MB) + wb (0.4 MB)
  ushort* qb = (ushort*)d_ws;
  ushort* kb = qb + Q_;
  ushort* vb = kb + Q_;
  float* part = (float*)(vb + Q_);
  float* kvf  = part + (size_t)NH_*NCH*4096;
  ushort* wb  = (ushort*)(kvf + (size_t)NH_*4096);

  conv_w       <<<dim3(192),       256, 0, stream>>>(qkv_w, wb);
  qkv_gemm_mfma<<<dim3(512, 3),    512, 0, stream>>>(x, wb, mask, qb, kb, vb);
  kv_partial   <<<dim3(NH_, NCH),  256, 0, stream>>>(kb, vb, part);
  kv_reduce    <<<dim3(NH_),       256, 0, stream>>>(part, kvf);
  attn_proj    <<<dim3(L_/64, N_), 256, 0, stream>>>(qb, vb, kvf, dconv_w,
                                                     proj_w, proj_b, out);
}

// Round 4
// 227.820 us; speedup vs baseline: 3.0085x; 1.8342x over previous
//
#include <hip/hip_runtime.h>
#include <math.h>

#define N_ 8
#define L_ 8192
#define C_ 256
#define H_ 4
#define D_ 64
#define NH_ (N_*H_)
#define NCH 16
#define CHUNK (L_/NCH)           // 512
#define Q_ ((size_t)N_*H_*L_*D_) // 16,777,216 elements per tensor

typedef float f32x4 __attribute__((ext_vector_type(4)));
typedef short short8 __attribute__((ext_vector_type(8)));

// bf16 helpers (manual, RNE) --------------------------------------------------
__device__ inline ushort f2b(float f){
  uint x = __float_as_uint(f);
  uint r = (x + 0x7fffu + ((x >> 16) & 1u)) >> 16;
  return (ushort)r;
}
__device__ inline float b2f(ushort u){
  return __uint_as_float(((uint)u) << 16);
}
__device__ inline uint pk2(float a, float b){
  return (uint)f2b(a) | ((uint)f2b(b) << 16);
}
__device__ inline void unpack8(uint4 p, float* f){
  f[0]=__uint_as_float(p.x<<16); f[1]=__uint_as_float(p.x&0xffff0000u);
  f[2]=__uint_as_float(p.y<<16); f[3]=__uint_as_float(p.y&0xffff0000u);
  f[4]=__uint_as_float(p.z<<16); f[5]=__uint_as_float(p.z&0xffff0000u);
  f[6]=__uint_as_float(p.w<<16); f[7]=__uint_as_float(p.w&0xffff0000u);
}

// ---------------------------------------------------------------------------
// K0: fp32 -> bf16 weight convert (generic, 1024 elems/block)
// ---------------------------------------------------------------------------
__global__ __launch_bounds__(256) void conv_w(const float* __restrict__ w,
                                              ushort* __restrict__ wb) {
  const int i = (blockIdx.x*256 + threadIdx.x) * 4;
  float4 f = *(const float4*)(w + i);
  *(ushort4*)&wb[i] = make_ushort4(f2b(f.x), f2b(f.y), f2b(f.z), f2b(f.w));
}

// ---------------------------------------------------------------------------
// K1: qkv = x @ qkv_w^T via bf16 MFMA, fused fp32->bf16 A-staging and
// mask + l2norm epilogue. BM=128, BN=256, BK=32, 512 thr = 8 waves (2Mx4N).
// ---------------------------------------------------------------------------
__global__ __launch_bounds__(512) void qkv_gemm_mfma(const float* __restrict__ x,
                                                     const ushort* __restrict__ wb,
                                                     const int* __restrict__ mask,
                                                     ushort* __restrict__ qb,
                                                     ushort* __restrict__ kb,
                                                     ushort* __restrict__ vb) {
  __shared__ ushort As[128][32];   // 8 KB  [m][k]
  __shared__ ushort Bs[256][32];   // 16 KB [n][k]
  const int tid = threadIdx.x;
  const int lane = tid & 63;
  const int wid = tid >> 6, wm = wid >> 2, wn = wid & 3;
  const int gm0 = blockIdx.x * 128;
  const int gn0 = blockIdx.y * 256;

  f32x4 acc[4][4] = {};

  const int ar = tid >> 2, akc = (tid & 3) << 3;
  const int br = tid >> 1, bkc = (tid & 1) << 4;

  for (int k0 = 0; k0 < C_; k0 += 32) {
    if (k0) __syncthreads();
    {
      const float* src = x + (size_t)(gm0 + ar)*C_ + k0 + akc;
      float4 f0 = *(const float4*)(src);
      float4 f1 = *(const float4*)(src + 4);
      uint4 p = make_uint4(pk2(f0.x,f0.y), pk2(f0.z,f0.w),
                           pk2(f1.x,f1.y), pk2(f1.z,f1.w));
      *(uint4*)&As[ar][akc] = p;
    }
    {
      const ushort* src = wb + (size_t)(gn0 + br)*C_ + k0 + bkc;
      uint4 p0 = *(const uint4*)(src);
      uint4 p1 = *(const uint4*)(src + 8);
      *(uint4*)&Bs[br][bkc]     = p0;
      *(uint4*)&Bs[br][bkc + 8] = p1;
    }
    __syncthreads();
    const int kc = (lane >> 4) << 3;
    short8 a[4], b[4];
#pragma unroll
    for (int mi = 0; mi < 4; ++mi)
      a[mi] = *(const short8*)&As[wm*64 + mi*16 + (lane & 15)][kc];
#pragma unroll
    for (int ni = 0; ni < 4; ++ni)
      b[ni] = *(const short8*)&Bs[wn*64 + ni*16 + (lane & 15)][kc];
#pragma unroll
    for (int mi = 0; mi < 4; ++mi)
#pragma unroll
      for (int ni = 0; ni < 4; ++ni)
        acc[mi][ni] = __builtin_amdgcn_mfma_f32_16x16x32_bf16(
            a[mi], b[ni], acc[mi][ni], 0, 0, 0);
  }

  const int sh = blockIdx.y*4 + wn;
  const int s = sh >> 2, h = sh & 3;
  ushort* dst = (s == 0) ? qb : (s == 1) ? kb : vb;
#pragma unroll
  for (int mi = 0; mi < 4; ++mi) {
    const int rbase = gm0 + wm*64 + mi*16 + ((lane >> 4) << 2);
#pragma unroll
    for (int j = 0; j < 4; ++j) {
      const int gr = rbase + j;
      const int nn = gr >> 13, l = gr & (L_-1);
      float v0 = acc[mi][0][j], v1 = acc[mi][1][j],
            v2 = acc[mi][2][j], v3 = acc[mi][3][j];
      if (s < 2) {
        float ss = v0*v0 + v1*v1 + v2*v2 + v3*v3;
        ss += __shfl_xor(ss, 1); ss += __shfl_xor(ss, 2);
        ss += __shfl_xor(ss, 4); ss += __shfl_xor(ss, 8);
        const float inv = 1.0f / sqrtf(ss);
        v0 *= inv; v1 *= inv; v2 *= inv; v3 *= inv;
      }
      const bool masked = (s == 0) && (mask[(size_t)nn*L_ + l] == 0);
      const size_t base = (((size_t)nn*H_ + h)*L_ + l)*D_ + (lane & 15);
      if (masked) {
        const ushort mb = 0xBE00u;  // bf16(-0.125)
        dst[base] = mb; dst[base+16] = mb; dst[base+32] = mb; dst[base+48] = mb;
      } else {
        dst[base]    = f2b(v0); dst[base+16] = f2b(v1);
        dst[base+32] = f2b(v2); dst[base+48] = f2b(v3);
      }
    }
  }
}

// ---------------------------------------------------------------------------
// K3: per (n,h,chunk): partial kv[d][e] = sum_l k_hat[l][d]*v[l][e]
// ---------------------------------------------------------------------------
__global__ __launch_bounds__(256) void kv_partial(const ushort* __restrict__ kb,
                                                  const ushort* __restrict__ vb,
                                                  float* __restrict__ part) {
  const int nh = blockIdx.x, ch = blockIdx.y;
  const size_t base = ((size_t)nh*L_ + (size_t)ch*CHUNK) * 64;
  __shared__ float ks[32][68];
  __shared__ float vs[32][68];
  const int tid = threadIdx.x;
  const int dB = tid >> 4, eB = tid & 15;
  const int lr = tid >> 3, lc = (tid & 7) << 3;
  float acc[4][4] = {};
  for (int l0 = 0; l0 < CHUNK; l0 += 32) {
    uint4 kp = *(const uint4*)(kb + base + (size_t)(l0+lr)*64 + lc);
    uint4 vp = *(const uint4*)(vb + base + (size_t)(l0+lr)*64 + lc);
    float kf[8], vf[8];
    unpack8(kp, kf); unpack8(vp, vf);
    *(float4*)&ks[lr][lc]   = make_float4(kf[0],kf[1],kf[2],kf[3]);
    *(float4*)&ks[lr][lc+4] = make_float4(kf[4],kf[5],kf[6],kf[7]);
    *(float4*)&vs[lr][lc]   = make_float4(vf[0],vf[1],vf[2],vf[3]);
    *(float4*)&vs[lr][lc+4] = make_float4(vf[4],vf[5],vf[6],vf[7]);
    __syncthreads();
#pragma unroll 8
    for (int l = 0; l < 32; ++l) {
      float4 k4 = *(const float4*)&ks[l][dB*4];
      float4 v4 = *(const float4*)&vs[l][eB*4];
      float kk[4] = {k4.x,k4.y,k4.z,k4.w};
      float vv[4] = {v4.x,v4.y,v4.z,v4.w};
#pragma unroll
      for (int i = 0; i < 4; ++i)
#pragma unroll
        for (int j = 0; j < 4; ++j)
          acc[i][j] += kk[i]*vv[j];
    }
    __syncthreads();
  }
  float* P = part + ((size_t)nh*NCH + ch)*4096;
#pragma unroll
  for (int i = 0; i < 4; ++i)
#pragma unroll
    for (int j = 0; j < 4; ++j)
      P[(dB*4+i)*64 + eB*4+j] = acc[i][j];
}

// ---------------------------------------------------------------------------
// K4: reduce partials, fold 1/pi, write TRANSPOSED bf16 kv: kvbT[e][d]
// ---------------------------------------------------------------------------
__global__ __launch_bounds__(256) void kv_reduce(const float* __restrict__ part,
                                                 ushort* __restrict__ kvbT) {
  const int nh = blockIdx.x;
  for (int i = threadIdx.x; i < 4096; i += 256) {
    float s = 0.f;
#pragma unroll
    for (int c = 0; c < NCH; ++c)
      s += part[((size_t)nh*NCH + c)*4096 + i];
    const int d = i >> 6, e = i & 63;
    kvbT[(size_t)nh*4096 + e*64 + d] = f2b(s * 0.31830988618379067f);
  }
}

// ---------------------------------------------------------------------------
// K5: MFMA attn+proj. Block = (n, 64 l-rows), 256 thr = 4 waves.
// Phase A: wave w = head w: t = q_hat @ kv' (MFMA) + 0.5v; l2norm; +conv9;
//          -> attn_s bf16 LDS.
// Phase B: wave w = out-col quadrant w: out = attn_s @ pwb^T + pb (MFMA).
// ---------------------------------------------------------------------------
__global__ __launch_bounds__(256) void attn_proj2(const ushort* __restrict__ qb,
                                                  const ushort* __restrict__ vb,
                                                  const ushort* __restrict__ kvbT,
                                                  const float* __restrict__ dwc,
                                                  const ushort* __restrict__ pwb,
                                                  const float* __restrict__ pb,
                                                  float* __restrict__ out) {
  __shared__ ushort vsm[4][72][72];   // 41472 B, 16B-aligned rows
  __shared__ ushort attn_s[64][264];  // 33792 B
  const int tid = threadIdx.x;
  const int lane = tid & 63;
  const int w = tid >> 6;             // wave id: head (A) / out-quadrant (B)
  const int r15 = lane & 15, kg = lane >> 4;
  const int n = blockIdx.y;
  const int l0 = blockIdx.x * 64;

  // ---- stage v halo (all 4 heads), zero-padded ----
  for (int f = tid; f < 2304; f += 256) {
    const int h = f / 576, rem = f % 576;
    const int row = rem >> 3, c0 = (rem & 7) << 3;
    const int lg = l0 - 4 + row;
    uint4 val = make_uint4(0,0,0,0);
    if ((unsigned)lg < (unsigned)L_)
      val = *(const uint4*)(vb + (((size_t)(n*4+h)*L_ + lg) << 6) + c0);
    *(uint4*)&vsm[h][row][c0] = val;
  }

  // ---- phase A: q_hat @ kv' via MFMA (wave w = head w) ----
  const int nh = n*4 + w;
  f32x4 acc[4][4] = {};
  {
    const ushort* qbase = qb + ((size_t)nh*L_ + l0)*64;
    const ushort* kvb = kvbT + (size_t)nh*4096;
#pragma unroll
    for (int ks = 0; ks < 2; ++ks) {
      const int kofs = ks*32 + kg*8;
      short8 a[4], b[4];
#pragma unroll
      for (int mi = 0; mi < 4; ++mi)
        a[mi] = *(const short8*)(qbase + (size_t)(mi*16 + r15)*64 + kofs);
#pragma unroll
      for (int ni = 0; ni < 4; ++ni)
        b[ni] = *(const short8*)(kvb + (ni*16 + r15)*64 + kofs);
#pragma unroll
      for (int mi = 0; mi < 4; ++mi)
#pragma unroll
        for (int ni = 0; ni < 4; ++ni)
          acc[mi][ni] = __builtin_amdgcn_mfma_f32_16x16x32_bf16(
              a[mi], b[ni], acc[mi][ni], 0, 0, 0);
    }
  }
  float wcv[9];
#pragma unroll
  for (int j2 = 0; j2 < 9; ++j2) wcv[j2] = dwc[w*9 + j2];
  __syncthreads();

  // ---- per-element: +0.5v, l2norm over e, +conv9, write attn_s ----
#pragma unroll
  for (int mi = 0; mi < 4; ++mi) {
#pragma unroll
    for (int j = 0; j < 4; ++j) {
      const int r = mi*16 + kg*4 + j;
      float t[4];
#pragma unroll
      for (int ni = 0; ni < 4; ++ni) {
        const int e = ni*16 + r15;
        t[ni] = acc[mi][ni][j] + 0.5f * b2f(vsm[w][r+4][e]);
      }
      float ss = t[0]*t[0] + t[1]*t[1] + t[2]*t[2] + t[3]*t[3];
      ss += __shfl_xor(ss, 1); ss += __shfl_xor(ss, 2);
      ss += __shfl_xor(ss, 4); ss += __shfl_xor(ss, 8);
      const float inv = 1.0f / sqrtf(ss);
#pragma unroll
      for (int ni = 0; ni < 4; ++ni) {
        const int e = ni*16 + r15;
        float cv = 0.f;
#pragma unroll
        for (int jj = 0; jj < 9; ++jj) cv += b2f(vsm[w][r+jj][e]) * wcv[jj];
        attn_s[r][w*64 + e] = f2b(t[ni]*inv + cv);
      }
    }
  }
  __syncthreads();

  // ---- phase B: out quadrant w = attn_s @ pwb^T + pb ----
  f32x4 acc2[4][4] = {};
  const ushort* pwq = pwb + (size_t)(w*64)*256;
#pragma unroll
  for (int ks = 0; ks < 8; ++ks) {
    const int kofs = ks*32 + kg*8;
    short8 a[4], b[4];
#pragma unroll
    for (int mi = 0; mi < 4; ++mi)
      a[mi] = *(const short8*)&attn_s[mi*16 + r15][kofs];
#pragma unroll
    for (int ni = 0; ni < 4; ++ni)
      b[ni] = *(const short8*)(pwq + (size_t)(ni*16 + r15)*256 + kofs);
#pragma unroll
    for (int mi = 0; mi < 4; ++mi)
#pragma unroll
      for (int ni = 0; ni < 4; ++ni)
        acc2[mi][ni] = __builtin_amdgcn_mfma_f32_16x16x32_bf16(
            a[mi], b[ni], acc2[mi][ni], 0, 0, 0);
  }
#pragma unroll
  for (int ni = 0; ni < 4; ++ni) {
    const int o = w*64 + ni*16 + r15;
    const float bias = pb[o];
#pragma unroll
    for (int mi = 0; mi < 4; ++mi) {
#pragma unroll
      for (int j = 0; j < 4; ++j) {
        const int l = l0 + mi*16 + kg*4 + j;
        out[((size_t)n*L_ + l)*C_ + o] = acc2[mi][ni][j] + bias;
      }
    }
  }
}

extern "C" void kernel_launch(void* const* d_in, const int* in_sizes, int n_in,
                              void* d_out, int out_size, void* d_ws, size_t ws_size,
                              hipStream_t stream) {
  const float* x      = (const float*)d_in[0];
  const int*   mask   = (const int*)d_in[1];
  const float* qkv_w  = (const float*)d_in[2];
  const float* proj_w = (const float*)d_in[3];
  const float* proj_b = (const float*)d_in[4];
  const float* dconv_w= (const float*)d_in[5];
  float* out = (float*)d_out;

  // workspace: 3 bf16 tensors (96 MB) + partials (8 MB) + kvbT/wb/pwb (<1 MB)
  ushort* qb = (ushort*)d_ws;
  ushort* kb = qb + Q_;
  ushort* vb = kb + Q_;
  float* part  = (float*)(vb + Q_);
  ushort* kvbT = (ushort*)(part + (size_t)NH_*NCH*4096);
  ushort* wb   = kvbT + (size_t)NH_*4096;
  ushort* pwb  = wb + 768*256;

  conv_w       <<<dim3(192),       256, 0, stream>>>(qkv_w, wb);
  conv_w       <<<dim3(64),        256, 0, stream>>>(proj_w, pwb);
  qkv_gemm_mfma<<<dim3(512, 3),    512, 0, stream>>>(x, wb, mask, qb, kb, vb);
  kv_partial   <<<dim3(NH_, NCH),  256, 0, stream>>>(kb, vb, part);
  kv_reduce    <<<dim3(NH_),       256, 0, stream>>>(part, kvbT);
  attn_proj2   <<<dim3(L_/64, N_), 256, 0, stream>>>(qb, vb, kvbT, dconv_w,
                                                     proj_w ? pwb : pwb, proj_b, out);
}

// Round 5
// 209.125 us; speedup vs baseline: 3.2774x; 1.0894x over previous
//
#include <hip/hip_runtime.h>
#include <math.h>

#define N_ 8
#define L_ 8192
#define C_ 256
#define H_ 4
#define D_ 64
#define NH_ (N_*H_)
#define NCH 16
#define CHUNK (L_/NCH)           // 512
#define Q_ ((size_t)N_*H_*L_*D_) // 16,777,216 elements per tensor

typedef float f32x4 __attribute__((ext_vector_type(4)));
typedef short short8 __attribute__((ext_vector_type(8)));

// bf16 helpers (manual, RNE) --------------------------------------------------
__device__ inline ushort f2b(float f){
  uint x = __float_as_uint(f);
  uint r = (x + 0x7fffu + ((x >> 16) & 1u)) >> 16;
  return (ushort)r;
}
__device__ inline float b2f(ushort u){
  return __uint_as_float(((uint)u) << 16);
}
__device__ inline uint pk2(float a, float b){
  return (uint)f2b(a) | ((uint)f2b(b) << 16);
}
__device__ inline void unpack8(uint4 p, float* f){
  f[0]=__uint_as_float(p.x<<16); f[1]=__uint_as_float(p.x&0xffff0000u);
  f[2]=__uint_as_float(p.y<<16); f[3]=__uint_as_float(p.y&0xffff0000u);
  f[4]=__uint_as_float(p.z<<16); f[5]=__uint_as_float(p.z&0xffff0000u);
  f[6]=__uint_as_float(p.w<<16); f[7]=__uint_as_float(p.w&0xffff0000u);
}

#define GLD16(g, l) __builtin_amdgcn_global_load_lds( \
    (const __attribute__((address_space(1))) void*)(g), \
    (__attribute__((address_space(3))) void*)(l), 16, 0, 0)

// ---------------------------------------------------------------------------
// K0: fp32 -> bf16 convert (1024 elems per block)
// ---------------------------------------------------------------------------
__global__ __launch_bounds__(256) void conv_w(const float* __restrict__ w,
                                              ushort* __restrict__ wb) {
  const int i = (blockIdx.x*256 + threadIdx.x) * 4;
  float4 f = *(const float4*)(w + i);
  *(ushort4*)&wb[i] = make_ushort4(f2b(f.x), f2b(f.y), f2b(f.z), f2b(f.w));
}

// ---------------------------------------------------------------------------
// K1: qkv = xb @ wb^T via bf16 MFMA. BM=128, BN=256, BK=64, 512 thr = 8 waves
// (2Mx4N, wave tile 64x64 = one (s,h) block). global_load_lds(16B) staging
// with rule-21 swizzle: linear LDS dest, inverse-swizzled global source col,
// XOR-swizzled ds_read. Fused mask + l2norm epilogue. Writes bf16 (N,H,L,D).
// ---------------------------------------------------------------------------
__global__ __launch_bounds__(512) void qkv_gemm_mfma2(const ushort* __restrict__ xb,
                                                      const ushort* __restrict__ wb,
                                                      const int* __restrict__ mask,
                                                      ushort* __restrict__ qb,
                                                      ushort* __restrict__ kb,
                                                      ushort* __restrict__ vb) {
  __shared__ ushort As[128][64];   // 16 KB, linear (gload_lds dest)
  __shared__ ushort Bs[256][64];   // 32 KB, linear
  const int tid  = threadIdx.x;
  const int lane = tid & 63;
  const int wid  = tid >> 6, wm = wid >> 2, wn = wid & 3;
  const int r15  = lane & 15, kg = lane >> 4;
  const int lrow8 = lane >> 3;     // row within an 8-row gload group
  const int lgrp  = lane & 7;      // 16B column group 0..7
  const int gm0 = blockIdx.x * 128;
  const int gn0 = blockIdx.y * 256;

  f32x4 acc[4][4] = {};

  for (int k0 = 0; k0 < C_; k0 += 64) {
    if (k0) __syncthreads();
    // A: wave stages rows [wid*16, wid*16+16): 2 gloads of 8 rows each.
    // LDS linear; global col-group pre-swizzled by row&7 (involution).
#pragma unroll
    for (int r = 0; r < 2; ++r) {
      const int row = wid*16 + r*8 + lrow8;
      const int gc  = k0 + ((lgrp ^ (row & 7)) << 3);
      GLD16(xb + (size_t)(gm0 + row)*C_ + gc, &As[wid*16 + r*8][0]);
    }
    // B: wave stages rows [wid*32, wid*32+32): 4 gloads.
#pragma unroll
    for (int r = 0; r < 4; ++r) {
      const int row = wid*32 + r*8 + lrow8;
      const int gc  = k0 + ((lgrp ^ (row & 7)) << 3);
      GLD16(wb + (size_t)(gn0 + row)*C_ + gc, &Bs[wid*32 + r*8][0]);
    }
    __syncthreads();
#pragma unroll
    for (int ks = 0; ks < 2; ++ks) {
      short8 a[4], b[4];
#pragma unroll
      for (int mi = 0; mi < 4; ++mi) {
        const int row = wm*64 + mi*16 + r15;
        a[mi] = *(const short8*)&As[row][((ks*4 + kg) ^ (row & 7)) << 3];
      }
#pragma unroll
      for (int ni = 0; ni < 4; ++ni) {
        const int row = wn*64 + ni*16 + r15;
        b[ni] = *(const short8*)&Bs[row][((ks*4 + kg) ^ (row & 7)) << 3];
      }
#pragma unroll
      for (int mi = 0; mi < 4; ++mi)
#pragma unroll
        for (int ni = 0; ni < 4; ++ni)
          acc[mi][ni] = __builtin_amdgcn_mfma_f32_16x16x32_bf16(
              a[mi], b[ni], acc[mi][ni], 0, 0, 0);
    }
  }

  // epilogue (unchanged, verified): C/D layout col=lane&15, row=(lane>>4)*4+j
  const int sh = blockIdx.y*4 + wn;
  const int s = sh >> 2, h = sh & 3;
  ushort* dst = (s == 0) ? qb : (s == 1) ? kb : vb;
#pragma unroll
  for (int mi = 0; mi < 4; ++mi) {
    const int rbase = gm0 + wm*64 + mi*16 + (kg << 2);
#pragma unroll
    for (int j = 0; j < 4; ++j) {
      const int gr = rbase + j;
      const int nn = gr >> 13, l = gr & (L_-1);
      float v0 = acc[mi][0][j], v1 = acc[mi][1][j],
            v2 = acc[mi][2][j], v3 = acc[mi][3][j];
      if (s < 2) {
        float ss = v0*v0 + v1*v1 + v2*v2 + v3*v3;
        ss += __shfl_xor(ss, 1); ss += __shfl_xor(ss, 2);
        ss += __shfl_xor(ss, 4); ss += __shfl_xor(ss, 8);
        const float inv = 1.0f / sqrtf(ss);
        v0 *= inv; v1 *= inv; v2 *= inv; v3 *= inv;
      }
      const bool masked = (s == 0) && (mask[(size_t)nn*L_ + l] == 0);
      const size_t base = (((size_t)nn*H_ + h)*L_ + l)*D_ + r15;
      if (masked) {
        const ushort mb = 0xBE00u;  // bf16(-0.125)
        dst[base] = mb; dst[base+16] = mb; dst[base+32] = mb; dst[base+48] = mb;
      } else {
        dst[base]    = f2b(v0); dst[base+16] = f2b(v1);
        dst[base+32] = f2b(v2); dst[base+48] = f2b(v3);
      }
    }
  }
}

// ---------------------------------------------------------------------------
// K3: per (n,h,chunk): partial kv[d][e] = sum_l k_hat[l][d]*v[l][e]
// ---------------------------------------------------------------------------
__global__ __launch_bounds__(256) void kv_partial(const ushort* __restrict__ kb,
                                                  const ushort* __restrict__ vb,
                                                  float* __restrict__ part) {
  const int nh = blockIdx.x, ch = blockIdx.y;
  const size_t base = ((size_t)nh*L_ + (size_t)ch*CHUNK) * 64;
  __shared__ float ks[32][68];
  __shared__ float vs[32][68];
  const int tid = threadIdx.x;
  const int dB = tid >> 4, eB = tid & 15;
  const int lr = tid >> 3, lc = (tid & 7) << 3;
  float acc[4][4] = {};
  for (int l0 = 0; l0 < CHUNK; l0 += 32) {
    uint4 kp = *(const uint4*)(kb + base + (size_t)(l0+lr)*64 + lc);
    uint4 vp = *(const uint4*)(vb + base + (size_t)(l0+lr)*64 + lc);
    float kf[8], vf[8];
    unpack8(kp, kf); unpack8(vp, vf);
    *(float4*)&ks[lr][lc]   = make_float4(kf[0],kf[1],kf[2],kf[3]);
    *(float4*)&ks[lr][lc+4] = make_float4(kf[4],kf[5],kf[6],kf[7]);
    *(float4*)&vs[lr][lc]   = make_float4(vf[0],vf[1],vf[2],vf[3]);
    *(float4*)&vs[lr][lc+4] = make_float4(vf[4],vf[5],vf[6],vf[7]);
    __syncthreads();
#pragma unroll 8
    for (int l = 0; l < 32; ++l) {
      float4 k4 = *(const float4*)&ks[l][dB*4];
      float4 v4 = *(const float4*)&vs[l][eB*4];
      float kk[4] = {k4.x,k4.y,k4.z,k4.w};
      float vv[4] = {v4.x,v4.y,v4.z,v4.w};
#pragma unroll
      for (int i = 0; i < 4; ++i)
#pragma unroll
        for (int j = 0; j < 4; ++j)
          acc[i][j] += kk[i]*vv[j];
    }
    __syncthreads();
  }
  float* P = part + ((size_t)nh*NCH + ch)*4096;
#pragma unroll
  for (int i = 0; i < 4; ++i)
#pragma unroll
    for (int j = 0; j < 4; ++j)
      P[(dB*4+i)*64 + eB*4+j] = acc[i][j];
}

// ---------------------------------------------------------------------------
// K4: reduce partials, fold 1/pi, write TRANSPOSED bf16 kv: kvbT[e][d]
// ---------------------------------------------------------------------------
__global__ __launch_bounds__(256) void kv_reduce(const float* __restrict__ part,
                                                 ushort* __restrict__ kvbT) {
  const int nh = blockIdx.x;
  for (int i = threadIdx.x; i < 4096; i += 256) {
    float s = 0.f;
#pragma unroll
    for (int c = 0; c < NCH; ++c)
      s += part[((size_t)nh*NCH + c)*4096 + i];
    const int d = i >> 6, e = i & 63;
    kvbT[(size_t)nh*4096 + e*64 + d] = f2b(s * 0.31830988618379067f);
  }
}

// ---------------------------------------------------------------------------
// K5: MFMA attn+proj. Block = (n, 64 l-rows), 256 thr = 4 waves.
// ---------------------------------------------------------------------------
__global__ __launch_bounds__(256) void attn_proj2(const ushort* __restrict__ qb,
                                                  const ushort* __restrict__ vb,
                                                  const ushort* __restrict__ kvbT,
                                                  const float* __restrict__ dwc,
                                                  const ushort* __restrict__ pwb,
                                                  const float* __restrict__ pb,
                                                  float* __restrict__ out) {
  __shared__ ushort vsm[4][72][72];   // 41472 B
  __shared__ ushort attn_s[64][264];  // 33792 B
  const int tid = threadIdx.x;
  const int lane = tid & 63;
  const int w = tid >> 6;
  const int r15 = lane & 15, kg = lane >> 4;
  const int n = blockIdx.y;
  const int l0 = blockIdx.x * 64;

  for (int f = tid; f < 2304; f += 256) {
    const int h = f / 576, rem = f % 576;
    const int row = rem >> 3, c0 = (rem & 7) << 3;
    const int lg = l0 - 4 + row;
    uint4 val = make_uint4(0,0,0,0);
    if ((unsigned)lg < (unsigned)L_)
      val = *(const uint4*)(vb + (((size_t)(n*4+h)*L_ + lg) << 6) + c0);
    *(uint4*)&vsm[h][row][c0] = val;
  }

  const int nh = n*4 + w;
  f32x4 acc[4][4] = {};
  {
    const ushort* qbase = qb + ((size_t)nh*L_ + l0)*64;
    const ushort* kvb = kvbT + (size_t)nh*4096;
#pragma unroll
    for (int ks = 0; ks < 2; ++ks) {
      const int kofs = ks*32 + kg*8;
      short8 a[4], b[4];
#pragma unroll
      for (int mi = 0; mi < 4; ++mi)
        a[mi] = *(const short8*)(qbase + (size_t)(mi*16 + r15)*64 + kofs);
#pragma unroll
      for (int ni = 0; ni < 4; ++ni)
        b[ni] = *(const short8*)(kvb + (ni*16 + r15)*64 + kofs);
#pragma unroll
      for (int mi = 0; mi < 4; ++mi)
#pragma unroll
        for (int ni = 0; ni < 4; ++ni)
          acc[mi][ni] = __builtin_amdgcn_mfma_f32_16x16x32_bf16(
              a[mi], b[ni], acc[mi][ni], 0, 0, 0);
    }
  }
  float wcv[9];
#pragma unroll
  for (int j2 = 0; j2 < 9; ++j2) wcv[j2] = dwc[w*9 + j2];
  __syncthreads();

#pragma unroll
  for (int mi = 0; mi < 4; ++mi) {
#pragma unroll
    for (int j = 0; j < 4; ++j) {
      const int r = mi*16 + kg*4 + j;
      float t[4];
#pragma unroll
      for (int ni = 0; ni < 4; ++ni) {
        const int e = ni*16 + r15;
        t[ni] = acc[mi][ni][j] + 0.5f * b2f(vsm[w][r+4][e]);
      }
      float ss = t[0]*t[0] + t[1]*t[1] + t[2]*t[2] + t[3]*t[3];
      ss += __shfl_xor(ss, 1); ss += __shfl_xor(ss, 2);
      ss += __shfl_xor(ss, 4); ss += __shfl_xor(ss, 8);
      const float inv = 1.0f / sqrtf(ss);
#pragma unroll
      for (int ni = 0; ni < 4; ++ni) {
        const int e = ni*16 + r15;
        float cv = 0.f;
#pragma unroll
        for (int jj = 0; jj < 9; ++jj) cv += b2f(vsm[w][r+jj][e]) * wcv[jj];
        attn_s[r][w*64 + e] = f2b(t[ni]*inv + cv);
      }
    }
  }
  __syncthreads();

  f32x4 acc2[4][4] = {};
  const ushort* pwq = pwb + (size_t)(w*64)*256;
#pragma unroll
  for (int ks = 0; ks < 8; ++ks) {
    const int kofs = ks*32 + kg*8;
    short8 a[4], b[4];
#pragma unroll
    for (int mi = 0; mi < 4; ++mi)
      a[mi] = *(const short8*)&attn_s[mi*16 + r15][kofs];
#pragma unroll
    for (int ni = 0; ni < 4; ++ni)
      b[ni] = *(const short8*)(pwq + (size_t)(ni*16 + r15)*256 + kofs);
#pragma unroll
    for (int mi = 0; mi < 4; ++mi)
#pragma unroll
      for (int ni = 0; ni < 4; ++ni)
        acc2[mi][ni] = __builtin_amdgcn_mfma_f32_16x16x32_bf16(
            a[mi], b[ni], acc2[mi][ni], 0, 0, 0);
  }
#pragma unroll
  for (int ni = 0; ni < 4; ++ni) {
    const int o = w*64 + ni*16 + r15;
    const float bias = pb[o];
#pragma unroll
    for (int mi = 0; mi < 4; ++mi) {
#pragma unroll
      for (int j = 0; j < 4; ++j) {
        const int l = l0 + mi*16 + kg*4 + j;
        out[((size_t)n*L_ + l)*C_ + o] = acc2[mi][ni][j] + bias;
      }
    }
  }
}

extern "C" void kernel_launch(void* const* d_in, const int* in_sizes, int n_in,
                              void* d_out, int out_size, void* d_ws, size_t ws_size,
                              hipStream_t stream) {
  const float* x      = (const float*)d_in[0];
  const int*   mask   = (const int*)d_in[1];
  const float* qkv_w  = (const float*)d_in[2];
  const float* proj_w = (const float*)d_in[3];
  const float* proj_b = (const float*)d_in[4];
  const float* dconv_w= (const float*)d_in[5];
  float* out = (float*)d_out;

  // ws: q/k/v bf16 (96 MB) + partials (8 MB) + xb (32 MB) + weights (<1 MB)
  ushort* qb = (ushort*)d_ws;
  ushort* kb = qb + Q_;
  ushort* vb = kb + Q_;
  float* part  = (float*)(vb + Q_);
  ushort* kvbT = (ushort*)(part + (size_t)NH_*NCH*4096);
  ushort* wb   = kvbT + (size_t)NH_*4096;
  ushort* pwb  = wb + 768*256;
  ushort* xb   = pwb + 256*256;

  conv_w        <<<dim3(16384),     256, 0, stream>>>(x, xb);        // x -> bf16
  conv_w        <<<dim3(192),       256, 0, stream>>>(qkv_w, wb);
  conv_w        <<<dim3(64),        256, 0, stream>>>(proj_w, pwb);
  qkv_gemm_mfma2<<<dim3(512, 3),    512, 0, stream>>>(xb, wb, mask, qb, kb, vb);
  kv_partial    <<<dim3(NH_, NCH),  256, 0, stream>>>(kb, vb, part);
  kv_reduce     <<<dim3(NH_),       256, 0, stream>>>(part, kvbT);
  attn_proj2    <<<dim3(L_/64, N_), 256, 0, stream>>>(qb, vb, kvbT, dconv_w,
                                                      pwb, proj_b, out);
}

// Round 6
// 184.493 us; speedup vs baseline: 3.7150x; 1.1335x over previous
//
#include <hip/hip_runtime.h>
#include <math.h>

#define N_ 8
#define L_ 8192
#define C_ 256
#define H_ 4
#define D_ 64
#define NH_ (N_*H_)
#define NCH 16
#define CHUNK (L_/NCH)           // 512
#define Q_ ((size_t)N_*H_*L_*D_) // 16,777,216 elements per tensor

typedef float f32x4 __attribute__((ext_vector_type(4)));
typedef short short8 __attribute__((ext_vector_type(8)));

// bf16 helpers (manual, RNE) --------------------------------------------------
__device__ inline ushort f2b(float f){
  uint x = __float_as_uint(f);
  uint r = (x + 0x7fffu + ((x >> 16) & 1u)) >> 16;
  return (ushort)r;
}
__device__ inline float b2f(ushort u){
  return __uint_as_float(((uint)u) << 16);
}
__device__ inline uint pk2(float a, float b){
  return (uint)f2b(a) | ((uint)f2b(b) << 16);
}
__device__ inline void unpack8(uint4 p, float* f){
  f[0]=__uint_as_float(p.x<<16); f[1]=__uint_as_float(p.x&0xffff0000u);
  f[2]=__uint_as_float(p.y<<16); f[3]=__uint_as_float(p.y&0xffff0000u);
  f[4]=__uint_as_float(p.z<<16); f[5]=__uint_as_float(p.z&0xffff0000u);
  f[6]=__uint_as_float(p.w<<16); f[7]=__uint_as_float(p.w&0xffff0000u);
}

#define GLD16(g, l) __builtin_amdgcn_global_load_lds( \
    (const __attribute__((address_space(1))) void*)(g), \
    (__attribute__((address_space(3))) void*)(l), 16, 0, 0)

// ---------------------------------------------------------------------------
// K0: fp32 -> bf16 convert (1024 elems per block)
// ---------------------------------------------------------------------------
__global__ __launch_bounds__(256) void conv_w(const float* __restrict__ w,
                                              ushort* __restrict__ wb) {
  const int i = (blockIdx.x*256 + threadIdx.x) * 4;
  float4 f = *(const float4*)(w + i);
  *(ushort4*)&wb[i] = make_ushort4(f2b(f.x), f2b(f.y), f2b(f.z), f2b(f.w));
}

// ---------------------------------------------------------------------------
// K1: qkv = xb @ wb^T via bf16 MFMA (unchanged, verified)
// ---------------------------------------------------------------------------
__global__ __launch_bounds__(512) void qkv_gemm_mfma2(const ushort* __restrict__ xb,
                                                      const ushort* __restrict__ wb,
                                                      const int* __restrict__ mask,
                                                      ushort* __restrict__ qb,
                                                      ushort* __restrict__ kb,
                                                      ushort* __restrict__ vb) {
  __shared__ ushort As[128][64];
  __shared__ ushort Bs[256][64];
  const int tid  = threadIdx.x;
  const int lane = tid & 63;
  const int wid  = tid >> 6, wm = wid >> 2, wn = wid & 3;
  const int r15  = lane & 15, kg = lane >> 4;
  const int lrow8 = lane >> 3;
  const int lgrp  = lane & 7;
  const int gm0 = blockIdx.x * 128;
  const int gn0 = blockIdx.y * 256;

  f32x4 acc[4][4] = {};

  for (int k0 = 0; k0 < C_; k0 += 64) {
    if (k0) __syncthreads();
#pragma unroll
    for (int r = 0; r < 2; ++r) {
      const int row = wid*16 + r*8 + lrow8;
      const int gc  = k0 + ((lgrp ^ (row & 7)) << 3);
      GLD16(xb + (size_t)(gm0 + row)*C_ + gc, &As[wid*16 + r*8][0]);
    }
#pragma unroll
    for (int r = 0; r < 4; ++r) {
      const int row = wid*32 + r*8 + lrow8;
      const int gc  = k0 + ((lgrp ^ (row & 7)) << 3);
      GLD16(wb + (size_t)(gn0 + row)*C_ + gc, &Bs[wid*32 + r*8][0]);
    }
    __syncthreads();
#pragma unroll
    for (int ks = 0; ks < 2; ++ks) {
      short8 a[4], b[4];
#pragma unroll
      for (int mi = 0; mi < 4; ++mi) {
        const int row = wm*64 + mi*16 + r15;
        a[mi] = *(const short8*)&As[row][((ks*4 + kg) ^ (row & 7)) << 3];
      }
#pragma unroll
      for (int ni = 0; ni < 4; ++ni) {
        const int row = wn*64 + ni*16 + r15;
        b[ni] = *(const short8*)&Bs[row][((ks*4 + kg) ^ (row & 7)) << 3];
      }
#pragma unroll
      for (int mi = 0; mi < 4; ++mi)
#pragma unroll
        for (int ni = 0; ni < 4; ++ni)
          acc[mi][ni] = __builtin_amdgcn_mfma_f32_16x16x32_bf16(
              a[mi], b[ni], acc[mi][ni], 0, 0, 0);
    }
  }

  const int sh = blockIdx.y*4 + wn;
  const int s = sh >> 2, h = sh & 3;
  ushort* dst = (s == 0) ? qb : (s == 1) ? kb : vb;
#pragma unroll
  for (int mi = 0; mi < 4; ++mi) {
    const int rbase = gm0 + wm*64 + mi*16 + (kg << 2);
#pragma unroll
    for (int j = 0; j < 4; ++j) {
      const int gr = rbase + j;
      const int nn = gr >> 13, l = gr & (L_-1);
      float v0 = acc[mi][0][j], v1 = acc[mi][1][j],
            v2 = acc[mi][2][j], v3 = acc[mi][3][j];
      if (s < 2) {
        float ss = v0*v0 + v1*v1 + v2*v2 + v3*v3;
        ss += __shfl_xor(ss, 1); ss += __shfl_xor(ss, 2);
        ss += __shfl_xor(ss, 4); ss += __shfl_xor(ss, 8);
        const float inv = 1.0f / sqrtf(ss);
        v0 *= inv; v1 *= inv; v2 *= inv; v3 *= inv;
      }
      const bool masked = (s == 0) && (mask[(size_t)nn*L_ + l] == 0);
      const size_t base = (((size_t)nn*H_ + h)*L_ + l)*D_ + r15;
      if (masked) {
        const ushort mb = 0xBE00u;  // bf16(-0.125)
        dst[base] = mb; dst[base+16] = mb; dst[base+32] = mb; dst[base+48] = mb;
      } else {
        dst[base]    = f2b(v0); dst[base+16] = f2b(v1);
        dst[base+32] = f2b(v2); dst[base+48] = f2b(v3);
      }
    }
  }
}

// ---------------------------------------------------------------------------
// K3: per (n,h,chunk): partial kv[d][e] = sum_l k_hat[l][d]*v[l][e] (unchanged)
// ---------------------------------------------------------------------------
__global__ __launch_bounds__(256) void kv_partial(const ushort* __restrict__ kb,
                                                  const ushort* __restrict__ vb,
                                                  float* __restrict__ part) {
  const int nh = blockIdx.x, ch = blockIdx.y;
  const size_t base = ((size_t)nh*L_ + (size_t)ch*CHUNK) * 64;
  __shared__ float ks[32][68];
  __shared__ float vs[32][68];
  const int tid = threadIdx.x;
  const int dB = tid >> 4, eB = tid & 15;
  const int lr = tid >> 3, lc = (tid & 7) << 3;
  float acc[4][4] = {};
  for (int l0 = 0; l0 < CHUNK; l0 += 32) {
    uint4 kp = *(const uint4*)(kb + base + (size_t)(l0+lr)*64 + lc);
    uint4 vp = *(const uint4*)(vb + base + (size_t)(l0+lr)*64 + lc);
    float kf[8], vf[8];
    unpack8(kp, kf); unpack8(vp, vf);
    *(float4*)&ks[lr][lc]   = make_float4(kf[0],kf[1],kf[2],kf[3]);
    *(float4*)&ks[lr][lc+4] = make_float4(kf[4],kf[5],kf[6],kf[7]);
    *(float4*)&vs[lr][lc]   = make_float4(vf[0],vf[1],vf[2],vf[3]);
    *(float4*)&vs[lr][lc+4] = make_float4(vf[4],vf[5],vf[6],vf[7]);
    __syncthreads();
#pragma unroll 8
    for (int l = 0; l < 32; ++l) {
      float4 k4 = *(const float4*)&ks[l][dB*4];
      float4 v4 = *(const float4*)&vs[l][eB*4];
      float kk[4] = {k4.x,k4.y,k4.z,k4.w};
      float vv[4] = {v4.x,v4.y,v4.z,v4.w};
#pragma unroll
      for (int i = 0; i < 4; ++i)
#pragma unroll
        for (int j = 0; j < 4; ++j)
          acc[i][j] += kk[i]*vv[j];
    }
    __syncthreads();
  }
  float* P = part + ((size_t)nh*NCH + ch)*4096;
#pragma unroll
  for (int i = 0; i < 4; ++i)
#pragma unroll
    for (int j = 0; j < 4; ++j)
      P[(dB*4+i)*64 + eB*4+j] = acc[i][j];
}

// ---------------------------------------------------------------------------
// K4: reduce partials, fold 1/pi, write TRANSPOSED bf16 kv: kvbT[e][d]
// ---------------------------------------------------------------------------
__global__ __launch_bounds__(256) void kv_reduce(const float* __restrict__ part,
                                                 ushort* __restrict__ kvbT) {
  const int nh = blockIdx.x;
  for (int i = threadIdx.x; i < 4096; i += 256) {
    float s = 0.f;
#pragma unroll
    for (int c = 0; c < NCH; ++c)
      s += part[((size_t)nh*NCH + c)*4096 + i];
    const int d = i >> 6, e = i & 63;
    kvbT[(size_t)nh*4096 + e*64 + d] = f2b(s * 0.31830988618379067f);
  }
}

// ---------------------------------------------------------------------------
// K5: MFMA attn+proj, 32-row tiles. Block = (n, 32 l-rows), 4 waves.
// Phase A: wave w = head w: q_hat @ kv' (MFMA, direct global frags).
// Conv phase: lane = e col, wave = head: sliding 9-tap window -> attn_s.
// Norm phase: t=acc+0.5v, row l2norm (shfl), + conv (read back), -> attn_s.
// Phase B: wave w = out-col quadrant: out = attn_s @ pwb^T + pb (MFMA).
// ---------------------------------------------------------------------------
__global__ __launch_bounds__(256, 4) void attn_proj3(const ushort* __restrict__ qb,
                                                     const ushort* __restrict__ vb,
                                                     const ushort* __restrict__ kvbT,
                                                     const float* __restrict__ dwc,
                                                     const ushort* __restrict__ pwb,
                                                     const float* __restrict__ pb,
                                                     float* __restrict__ out) {
  __shared__ ushort vsm[4][40][72];   // 23040 B (rows l0-4 .. l0+35)
  __shared__ ushort attn_s[32][260];  // 16640 B
  const int tid = threadIdx.x;
  const int lane = tid & 63;
  const int w = tid >> 6;             // wave id: head (A/conv/norm), quadrant (B)
  const int r15 = lane & 15, kg = lane >> 4;
  const int n = blockIdx.y;
  const int l0 = blockIdx.x * 32;

  // ---- stage v halo (4 heads x 40 rows), zero-padded ----
  for (int f = tid; f < 1280; f += 256) {
    const int h = f / 320, rem = f % 320;
    const int row = rem >> 3, c0 = (rem & 7) << 3;
    const int lg = l0 - 4 + row;
    uint4 val = make_uint4(0,0,0,0);
    if ((unsigned)lg < (unsigned)L_)
      val = *(const uint4*)(vb + (((size_t)(n*4+h)*L_ + lg) << 6) + c0);
    *(uint4*)&vsm[h][row][c0] = val;
  }

  // ---- phase A: q_hat @ kv' via MFMA (wave w = head w), 32x64 ----
  const int nh = n*4 + w;
  f32x4 acc[2][4] = {};
  {
    const ushort* qbase = qb + ((size_t)nh*L_ + l0)*64;
    const ushort* kvb = kvbT + (size_t)nh*4096;
#pragma unroll
    for (int ks = 0; ks < 2; ++ks) {
      const int kofs = ks*32 + kg*8;
      short8 a[2], b[4];
#pragma unroll
      for (int mi = 0; mi < 2; ++mi)
        a[mi] = *(const short8*)(qbase + (size_t)(mi*16 + r15)*64 + kofs);
#pragma unroll
      for (int ni = 0; ni < 4; ++ni)
        b[ni] = *(const short8*)(kvb + (ni*16 + r15)*64 + kofs);
#pragma unroll
      for (int mi = 0; mi < 2; ++mi)
#pragma unroll
        for (int ni = 0; ni < 4; ++ni)
          acc[mi][ni] = __builtin_amdgcn_mfma_f32_16x16x32_bf16(
              a[mi], b[ni], acc[mi][ni], 0, 0, 0);
    }
  }
  __syncthreads();   // vsm staged

  // ---- conv phase: lane = e, wave = head; sliding 9-tap window ----
  {
    float wcv[9];
#pragma unroll
    for (int j = 0; j < 9; ++j) wcv[j] = dwc[w*9 + j];
    float win[9];
#pragma unroll
    for (int j = 0; j < 9; ++j) win[j] = b2f(vsm[w][j][lane]);
#pragma unroll
    for (int r = 0; r < 32; ++r) {
      float cv = 0.f;
#pragma unroll
      for (int j = 0; j < 9; ++j) cv += win[j] * wcv[j];
      attn_s[r][w*64 + lane] = f2b(cv);
      if (r < 31) {
#pragma unroll
        for (int j = 0; j < 8; ++j) win[j] = win[j+1];
        win[8] = b2f(vsm[w][r + 9][lane]);
      }
    }
  }
  __syncthreads();   // conv values ready

  // ---- norm phase: t = acc + 0.5v; row l2norm; + conv; -> attn_s ----
#pragma unroll
  for (int mi = 0; mi < 2; ++mi) {
#pragma unroll
    for (int j = 0; j < 4; ++j) {
      const int r = mi*16 + kg*4 + j;
      float t[4];
#pragma unroll
      for (int ni = 0; ni < 4; ++ni) {
        const int e = ni*16 + r15;
        t[ni] = acc[mi][ni][j] + 0.5f * b2f(vsm[w][r+4][e]);
      }
      float ss = t[0]*t[0] + t[1]*t[1] + t[2]*t[2] + t[3]*t[3];
      ss += __shfl_xor(ss, 1); ss += __shfl_xor(ss, 2);
      ss += __shfl_xor(ss, 4); ss += __shfl_xor(ss, 8);
      const float inv = 1.0f / sqrtf(ss);
#pragma unroll
      for (int ni = 0; ni < 4; ++ni) {
        const int e = ni*16 + r15;
        const float cv = b2f(attn_s[r][w*64 + e]);
        attn_s[r][w*64 + e] = f2b(t[ni]*inv + cv);
      }
    }
  }
  __syncthreads();   // attn tile final

  // ---- phase B: out quadrant w = attn_s @ pwb^T + pb ----
  f32x4 acc2[2][4] = {};
  const ushort* pwq = pwb + (size_t)(w*64)*256;
#pragma unroll
  for (int ks = 0; ks < 8; ++ks) {
    const int kofs = ks*32 + kg*8;
    short8 a[2], b[4];
#pragma unroll
    for (int mi = 0; mi < 2; ++mi)
      a[mi] = *(const short8*)&attn_s[mi*16 + r15][kofs];
#pragma unroll
    for (int ni = 0; ni < 4; ++ni)
      b[ni] = *(const short8*)(pwq + (size_t)(ni*16 + r15)*256 + kofs);
#pragma unroll
    for (int mi = 0; mi < 2; ++mi)
#pragma unroll
      for (int ni = 0; ni < 4; ++ni)
        acc2[mi][ni] = __builtin_amdgcn_mfma_f32_16x16x32_bf16(
            a[mi], b[ni], acc2[mi][ni], 0, 0, 0);
  }
#pragma unroll
  for (int ni = 0; ni < 4; ++ni) {
    const int o = w*64 + ni*16 + r15;
    const float bias = pb[o];
#pragma unroll
    for (int mi = 0; mi < 2; ++mi) {
#pragma unroll
      for (int j = 0; j < 4; ++j) {
        const int l = l0 + mi*16 + kg*4 + j;
        out[((size_t)n*L_ + l)*C_ + o] = acc2[mi][ni][j] + bias;
      }
    }
  }
}

extern "C" void kernel_launch(void* const* d_in, const int* in_sizes, int n_in,
                              void* d_out, int out_size, void* d_ws, size_t ws_size,
                              hipStream_t stream) {
  const float* x      = (const float*)d_in[0];
  const int*   mask   = (const int*)d_in[1];
  const float* qkv_w  = (const float*)d_in[2];
  const float* proj_w = (const float*)d_in[3];
  const float* proj_b = (const float*)d_in[4];
  const float* dconv_w= (const float*)d_in[5];
  float* out = (float*)d_out;

  // ws: q/k/v bf16 (96 MB) + partials (8 MB) + xb (32 MB) + weights (<1 MB)
  ushort* qb = (ushort*)d_ws;
  ushort* kb = qb + Q_;
  ushort* vb = kb + Q_;
  float* part  = (float*)(vb + Q_);
  ushort* kvbT = (ushort*)(part + (size_t)NH_*NCH*4096);
  ushort* wb   = kvbT + (size_t)NH_*4096;
  ushort* pwb  = wb + 768*256;
  ushort* xb   = pwb + 256*256;

  conv_w        <<<dim3(16384),     256, 0, stream>>>(x, xb);
  conv_w        <<<dim3(192),       256, 0, stream>>>(qkv_w, wb);
  conv_w        <<<dim3(64),        256, 0, stream>>>(proj_w, pwb);
  qkv_gemm_mfma2<<<dim3(512, 3),    512, 0, stream>>>(xb, wb, mask, qb, kb, vb);
  kv_partial    <<<dim3(NH_, NCH),  256, 0, stream>>>(kb, vb, part);
  kv_reduce     <<<dim3(NH_),       256, 0, stream>>>(part, kvbT);
  attn_proj3    <<<dim3(L_/32, N_), 256, 0, stream>>>(qb, vb, kvbT, dconv_w,
                                                      pwb, proj_b, out);
}